// Round 6
// baseline (679.345 us; speedup 1.0000x reference)
//
#include <hip/hip_runtime.h>

#define SLEN 200
#define NB   2048

typedef short  bf8s   __attribute__((ext_vector_type(8)));
typedef __bf16 bf16x8 __attribute__((ext_vector_type(8)));
typedef float  f4     __attribute__((ext_vector_type(4)));

__device__ __forceinline__ short fb1(float x){ __bf16 b=(__bf16)x; return __builtin_bit_cast(short,b); }
__device__ __forceinline__ float b2f(unsigned short b){
  return __builtin_bit_cast(float, ((unsigned int)b)<<16);
}
__device__ __forceinline__ float ldf(const void* p, long i, bool bf){
  return bf ? b2f(((const unsigned short*)p)[i]) : ((const float*)p)[i];
}
__device__ __forceinline__ float rcp_(float x){ return __builtin_amdgcn_rcpf(x); }
__device__ __forceinline__ float sigm(float x){ return rcp_(1.f + __expf(-x)); }
__device__ __forceinline__ float tanh_(float x){ return 1.f - 2.f*rcp_(1.f + __expf(2.f*x)); }
__device__ __forceinline__ f4 MF(bf8s a, bf8s b, f4 c){
  return __builtin_amdgcn_mfma_f32_16x16x32_bf16(
    __builtin_bit_cast(bf16x8,a), __builtin_bit_cast(bf16x8,b), c, 0,0,0);
}
// sigma: h'col v -> original col (0..63).  h'col(tt,m) layout chosen so each
// lane's D regs (col=batch) are exactly its own next-step B-frag k-slots.
__device__ __forceinline__ int sigmap(int v){
  int tt = (v<32) ? ((v>>2)&1) : (2 + ((v>>2)&1));
  int m  = 4*((v&31)>>3) + (v&3);
  return 16*tt + m;
}
// MFMA layouts (validated r3-r5): A/B: nonK=lane&15, k=8*(lane>>4)+j;
// D: col=lane&15, row=4*(lane>>4)+reg.

// ---------------- K0: input dtype detector ----------------
__global__ void k0_detect(const unsigned int* wds, int n, int* flag){
  __shared__ int cnt[256];
  int c = 0;
  for (int i = threadIdx.x; i < n; i += 256){
    unsigned e = (wds[i] >> 7) & 0xFFu;
    c += (e >= 96u && e <= 160u) ? 1 : 0;
  }
  cnt[threadIdx.x] = c;
  __syncthreads();
  for (int s = 128; s > 0; s >>= 1){
    if (threadIdx.x < s) cnt[threadIdx.x] += cnt[threadIdx.x + s];
    __syncthreads();
  }
  if (threadIdx.x == 0) flag[0] = (cnt[0]*2 > n) ? 1 : 0;
}

// ---------------- K0b: counting sort of rows by length ----------------
__global__ __launch_bounds__(256)
void k0_sort(const int* lengths, int* perm){
  __shared__ int hist[256];
  __shared__ int base[256];
  hist[threadIdx.x]=0;
  __syncthreads();
  for (int i=threadIdx.x;i<NB;i+=256) atomicAdd(&hist[lengths[i]&255],1);
  __syncthreads();
  if (threadIdx.x==0){ int acc=0; for (int j=0;j<256;++j){ base[j]=acc; acc+=hist[j]; } }
  __syncthreads();
  for (int i=threadIdx.x;i<NB;i+=256){
    int l=lengths[i]&255;
    int p=atomicAdd(&base[l],1);
    perm[p]=i;
  }
}

// ---------------- K1: GRU scan, single wave / 16 rows, barrier-free ----------------
__global__ __launch_bounds__(64,1)
void k1_gru(const void* behavior, const void* Wih, const void* Whh,
            const void* bih, const void* bhh, const int* lengths,
            const int* perm, const int* flag, unsigned short* hidden){
  const bool bf = flag[0]!=0;
  const int lane=threadIdx.x, l15=lane&15, q=lane>>4;
  __shared__ int rows16[16], lens16[16];
  if (lane<16){ int r=perm[blockIdx.x*16+lane]; rows16[lane]=r; lens16[lane]=lengths[r]; }
  asm volatile("s_waitcnt lgkmcnt(0)" ::: "memory");

  const int R = rows16[l15], lenB = lens16[l15];
  int maxlen=1;
#pragma unroll
  for (int i=0;i<16;++i) maxlen = max(maxlen, lens16[i]);
  const int ml1 = maxlen-1;

  // A-frags: weights.  wX (x-part, identity cols), wA (h-part, sigma cols).
  bf8s wX[3][4][2], wA[3][4][2];
#pragma unroll
  for (int g=0;g<3;++g)
#pragma unroll
   for (int tt=0;tt<4;++tt)
#pragma unroll
    for (int kf=0;kf<2;++kf){
      bf8s x_, a_;
#pragma unroll
      for (int j=0;j<8;++j){
        long row = 64*g + 16*tt + l15;
        x_[j] = fb1(ldf(Wih, row*64 + kf*32 + 8*q + j, bf));
        a_[j] = fb1(ldf(Whh, row*64 + sigmap(kf*32 + 8*q + j), bf));
      }
      wX[g][tt][kf]=x_; wA[g][tt][kf]=a_;
    }
  f4 Br[4],Bz[4],Bnx[4],Bnh[4];
#pragma unroll
  for (int tt=0;tt<4;++tt)
#pragma unroll
   for (int i=0;i<4;++i){
     int idx = 16*tt + 4*q + i;
     Br[tt][i]  = ldf(bih,idx,bf)+ldf(bhh,idx,bf);
     Bz[tt][i]  = ldf(bih,64+idx,bf)+ldf(bhh,64+idx,bf);
     Bnx[tt][i] = ldf(bih,128+idx,bf);
     Bnh[tt][i] = ldf(bhh,128+idx,bf);
   }

  float hf[16];
#pragma unroll
  for (int s=0;s<16;++s) hf[s]=0.f;
  bf8s hB0 = {0,0,0,0,0,0,0,0}, hB1 = {0,0,0,0,0,0,0,0};

  const unsigned short* bp=(const unsigned short*)behavior;
  const float*          fp=(const float*)behavior;
  const long xbase = ((long)R*SLEN)*64 + 8*q;

  bf8s xC0,xC1,xN0,xN1;
  f4 c0,c1,c2,c3, n0,n1,n2,n3;
  {
    long o0=xbase, o1=xbase+(long)min(1,ml1)*64;
    if (bf){
      xC0=*(const bf8s*)(bp+o0); xC1=*(const bf8s*)(bp+o0+32);
      xN0=*(const bf8s*)(bp+o1); xN1=*(const bf8s*)(bp+o1+32);
    } else {
      c0=*(const f4*)(fp+o0); c1=*(const f4*)(fp+o0+4); c2=*(const f4*)(fp+o0+32); c3=*(const f4*)(fp+o0+36);
      n0=*(const f4*)(fp+o1); n1=*(const f4*)(fp+o1+4); n2=*(const f4*)(fp+o1+32); n3=*(const f4*)(fp+o1+36);
    }
  }

  for (int t=0;t<maxlen;++t){
    // prefetch t+2
    long po = xbase + (long)min(t+2,ml1)*64;
    bf8s pN0,pN1; f4 p0,p1,p2,p3;
    if (bf){ pN0=*(const bf8s*)(bp+po); pN1=*(const bf8s*)(bp+po+32); }
    else   { p0=*(const f4*)(fp+po); p1=*(const f4*)(fp+po+4); p2=*(const f4*)(fp+po+32); p3=*(const f4*)(fp+po+36); }

    bf8s xu0, xu1;
    if (bf){ xu0=xC0; xu1=xC1; }
    else {
#pragma unroll
      for (int j=0;j<4;++j){
        xu0[j]=fb1(c0[j]); xu0[4+j]=fb1(c1[j]);
        xu1[j]=fb1(c2[j]); xu1[4+j]=fb1(c3[j]);
      }
    }

    f4 Dr[4],Dz[4],Dnx[4],Dnh[4];
#pragma unroll
    for (int tt=0;tt<4;++tt){ Dr[tt]=Br[tt]; Dz[tt]=Bz[tt]; Dnx[tt]=Bnx[tt]; Dnh[tt]=Bnh[tt]; }
#pragma unroll
    for (int tt=0;tt<4;++tt){
      Dr[tt] =MF(wX[0][tt][0],xu0,Dr[tt]);  Dr[tt] =MF(wX[0][tt][1],xu1,Dr[tt]);
      Dz[tt] =MF(wX[1][tt][0],xu0,Dz[tt]);  Dz[tt] =MF(wX[1][tt][1],xu1,Dz[tt]);
      Dnx[tt]=MF(wX[2][tt][0],xu0,Dnx[tt]); Dnx[tt]=MF(wX[2][tt][1],xu1,Dnx[tt]);
      Dr[tt] =MF(wA[0][tt][0],hB0,Dr[tt]);  Dr[tt] =MF(wA[0][tt][1],hB1,Dr[tt]);
      Dz[tt] =MF(wA[1][tt][0],hB0,Dz[tt]);  Dz[tt] =MF(wA[1][tt][1],hB1,Dz[tt]);
      Dnh[tt]=MF(wA[2][tt][0],hB0,Dnh[tt]); Dnh[tt]=MF(wA[2][tt][1],hB1,Dnh[tt]);
    }

    bf8s o0,o1;
#pragma unroll
    for (int s=0;s<16;++s){
      int tt=s>>2, i=s&3;
      float rg = sigm(Dr[tt][i]);
      float zg = sigm(Dz[tt][i]);
      float ng = tanh_(Dnx[tt][i] + rg*Dnh[tt][i]);
      float hn = ng + zg*(hf[s]-ng);
      hf[s] = (t<lenB) ? hn : hf[s];
      if (s<8) o0[s]=fb1(hf[s]); else o1[s-8]=fb1(hf[s]);
    }
    hB0=o0; hB1=o1;
    long ho = ((long)R*SLEN + t)*64 + 8*q;
    *(uint4*)(hidden+ho)    = __builtin_bit_cast(uint4,hB0);
    *(uint4*)(hidden+ho+32) = __builtin_bit_cast(uint4,hB1);

    if (bf){ xC0=xN0; xC1=xN1; xN0=pN0; xN1=pN1; }
    else   { c0=n0;c1=n1;c2=n2;c3=n3; n0=p0;n1=p1;n2=p2;n3=p3; }
  }
}

// ---------------- K2: attention MLP + masked softmax (sigma-aware) ----------------
__global__ __launch_bounds__(256)
void k2_att(const unsigned short* hidden, const void* target, const void* A1,
            const void* b1, const void* A2, const int* lengths, const int* flag,
            float* attw){
  const bool bf = flag[0]!=0;
  const int b=blockIdx.x, tid=threadIdx.x, lane=tid&63, w=tid>>6, l15=lane&15, q=lane>>4;
  __shared__ alignas(16) unsigned short hl[208][72];
  __shared__ float ctp[4][64];
  __shared__ float ct[64], a2s[64], tg[64], score[208], red[8];
  const int len = lengths[b];
  int mtiles = (len+15)>>4; if (mtiles>13) mtiles=13;

  if (tid<64){ tg[tid] = ldf(target,(long)b*64+tid,bf); a2s[tid]=ldf(A2,tid,bf); }
  for (int i=tid;i<mtiles*16*8;i+=256){
    int row=i>>3, c8=(i&7)*8;
    uint4 v = {0u,0u,0u,0u};
    if (row<SLEN) v = *(const uint4*)&hidden[((long)b*SLEN+row)*64 + c8];
    *(uint4*)&hl[row][c8] = v;
  }
  // B-frags of A1 h-part with sigma'd k columns (hidden is in h'-space)
  bf8s a1f[4][2];
#pragma unroll
  for (int nt=0;nt<4;++nt)
#pragma unroll
    for (int kf=0;kf<2;++kf){
      bf8s t_;
#pragma unroll
      for (int j=0;j<8;++j)
        t_[j] = fb1(ldf(A1,(long)(nt*16+l15)*128 + sigmap(kf*32+8*q+j), bf));
      a1f[nt][kf]=t_;
    }
  __syncthreads();

  {
    int a = tid&63, g = tid>>6;
    float part = 0.f;
#pragma unroll
    for (int k=0;k<16;++k) part += tg[g*16+k]*ldf(A1,(long)a*128+64+g*16+k,bf);
    ctp[g][a] = part;
  }
  __syncthreads();
  if (tid<64) ct[tid] = ldf(b1,tid,bf) + ctp[0][tid]+ctp[1][tid]+ctp[2][tid]+ctp[3][tid];
  __syncthreads();

  for (int m=w; m<mtiles; m+=4){
    int row = m*16 + l15;
    bf8s h0 = *(const bf8s*)&hl[row][q*8];
    bf8s h1 = *(const bf8s*)&hl[row][32+q*8];
    f4 z4={0.f,0.f,0.f,0.f};
    f4 acc[4];
#pragma unroll
    for (int nt=0;nt<4;++nt){
      f4 a=z4; a=MF(h0,a1f[nt][0],a); a=MF(h1,a1f[nt][1],a); acc[nt]=a;
    }
#pragma unroll
    for (int i=0;i<4;++i){
      float s=0.f;
#pragma unroll
      for (int nt=0;nt<4;++nt){
        int au = nt*16 + l15;
        s += fmaxf(acc[nt][i]+ct[au],0.f)*a2s[au];
      }
#pragma unroll
      for (int d=1; d<16; d<<=1) s += __shfl_xor(s,d);
      if (l15==0) score[m*16+4*q+i] = s;
    }
  }
  __syncthreads();

  bool valid = (tid<len);
  float sv = (tid<208 && valid)? score[tid] : -3e38f;
  float mv = sv;
#pragma unroll
  for (int d=32;d>0;d>>=1) mv = fmaxf(mv,__shfl_xor(mv,d));
  if (lane==0) red[w]=mv;
  __syncthreads();
  float M = fmaxf(fmaxf(red[0],red[1]),fmaxf(red[2],red[3]));
  float e = valid? __expf(sv-M):0.f;
  float sum=e;
#pragma unroll
  for (int d=32;d>0;d>>=1) sum += __shfl_xor(sum,d);
  if (lane==0) red[4+w]=sum;
  __syncthreads();
  float S = red[4]+red[5]+red[6]+red[7];
  float Si = rcp_(S);
  if (tid<SLEN) attw[(long)b*SLEN+tid]=e*Si;
}

// ---------------- K3: AGRU scan, single wave / 16 rows, barrier-free ----------------
__global__ __launch_bounds__(64,1)
void k3_agru(const unsigned short* hidden, const float* attw,
             const void* Wr, const void* br, const void* Wz, const void* bz,
             const void* Wn, const void* bn, const int* lengths,
             const int* perm, const int* flag, float* out){
  const bool bf = flag[0]!=0;
  const int lane=threadIdx.x, l15=lane&15, q=lane>>4;
  __shared__ int rows16[16], lens16[16];
  __shared__ float att_l[16][204];
  if (lane<16){ int r=perm[blockIdx.x*16+lane]; rows16[lane]=r; lens16[lane]=lengths[r]; }
  asm volatile("s_waitcnt lgkmcnt(0)" ::: "memory");

  const int R = rows16[l15];
  int maxlen=1;
#pragma unroll
  for (int i=0;i<16;++i) maxlen = max(maxlen, lens16[i]);
  const int ml1 = maxlen-1;

  for (int i=lane;i<16*50;i+=64){
    int s=i/50, c=(i-s*50)*4;
    *(f4*)&att_l[s][c] = *(const f4*)&attw[(long)rows16[s]*SLEN + c];
  }
  asm volatile("s_waitcnt lgkmcnt(0)" ::: "memory");

  bf8s wRhi[4][2], wRh[4][2], wZhi[4][2], wZh[4][2], wNhi[4][2], wNh[4][2];
#pragma unroll
  for (int tt=0;tt<4;++tt)
#pragma unroll
   for (int kf=0;kf<2;++kf){
     bf8s rhi_,rh_,zhi_,zh_,nhi_,nh_;
#pragma unroll
     for (int j=0;j<8;++j){
       long row = 16*tt + l15;
       int vs = sigmap(kf*32 + 8*q + j);
       rhi_[j]=fb1(ldf(Wr, row*128 + vs, bf));
       rh_ [j]=fb1(ldf(Wr, row*128 + 64 + vs, bf));
       zhi_[j]=fb1(ldf(Wz, row*128 + vs, bf));
       zh_ [j]=fb1(ldf(Wz, row*128 + 64 + vs, bf));
       nhi_[j]=fb1(ldf(Wn, row*128 + vs, bf));
       nh_ [j]=fb1(ldf(Wn, row*128 + 64 + vs, bf));
     }
     wRhi[tt][kf]=rhi_; wRh[tt][kf]=rh_;
     wZhi[tt][kf]=zhi_; wZh[tt][kf]=zh_;
     wNhi[tt][kf]=nhi_; wNh[tt][kf]=nh_;
   }
  f4 BR[4],BZ[4],BN[4];
#pragma unroll
  for (int tt=0;tt<4;++tt)
#pragma unroll
   for (int i=0;i<4;++i){
     int idx = 16*tt + 4*q + i;
     BR[tt][i]=ldf(br,idx,bf); BZ[tt][i]=ldf(bz,idx,bf); BN[tt][i]=ldf(bn,idx,bf);
   }

  float h3[16];
#pragma unroll
  for (int s=0;s<16;++s) h3[s]=0.f;
  bf8s h3B0={0,0,0,0,0,0,0,0}, h3B1={0,0,0,0,0,0,0,0};

  const long hbase = ((long)R*SLEN)*64 + 8*q;
  bf8s hiC0,hiC1,hiN0,hiN1;
  {
    long o0=hbase, o1=hbase+(long)min(1,ml1)*64;
    hiC0=*(const bf8s*)(hidden+o0); hiC1=*(const bf8s*)(hidden+o0+32);
    hiN0=*(const bf8s*)(hidden+o1); hiN1=*(const bf8s*)(hidden+o1+32);
  }

  for (int t=0;t<maxlen;++t){
    long po = hbase + (long)min(t+2,ml1)*64;
    bf8s pN0=*(const bf8s*)(hidden+po), pN1=*(const bf8s*)(hidden+po+32);
    float ai = att_l[l15][t];

    f4 Dr[4],Dz[4],Dn[4];
#pragma unroll
    for (int tt=0;tt<4;++tt){ Dr[tt]=BR[tt]; Dz[tt]=BZ[tt]; Dn[tt]=BN[tt]; }
#pragma unroll
    for (int tt=0;tt<4;++tt){
      Dr[tt]=MF(wRhi[tt][0],hiC0,Dr[tt]); Dr[tt]=MF(wRhi[tt][1],hiC1,Dr[tt]);
      Dr[tt]=MF(wRh [tt][0],h3B0,Dr[tt]); Dr[tt]=MF(wRh [tt][1],h3B1,Dr[tt]);
      Dz[tt]=MF(wZhi[tt][0],hiC0,Dz[tt]); Dz[tt]=MF(wZhi[tt][1],hiC1,Dz[tt]);
      Dz[tt]=MF(wZh [tt][0],h3B0,Dz[tt]); Dz[tt]=MF(wZh [tt][1],h3B1,Dz[tt]);
      Dn[tt]=MF(wNhi[tt][0],hiC0,Dn[tt]); Dn[tt]=MF(wNhi[tt][1],hiC1,Dn[tt]);
    }
    bf8s rb0,rb1;
#pragma unroll
    for (int s=0;s<16;++s){
      int tt=s>>2, i=s&3;
      float rg = sigm(Dr[tt][i]);
      float rh = rg*h3[s];
      if (s<8) rb0[s]=fb1(rh); else rb1[s-8]=fb1(rh);
    }
#pragma unroll
    for (int tt=0;tt<4;++tt){
      Dn[tt]=MF(wNh[tt][0],rb0,Dn[tt]); Dn[tt]=MF(wNh[tt][1],rb1,Dn[tt]);
    }
    bf8s o0,o1;
#pragma unroll
    for (int s=0;s<16;++s){
      int tt=s>>2, i=s&3;
      float zg = sigm(Dz[tt][i]) * ai;
      float ng = tanh_(Dn[tt][i]);
      float hn = h3[s] + zg*(ng - h3[s]);   // t>=len: ai=0 -> zg=0 -> exact hold
      h3[s] = hn;
      if (s<8) o0[s]=fb1(hn); else o1[s-8]=fb1(hn);
    }
    h3B0=o0; h3B1=o1;
    hiC0=hiN0; hiC1=hiN1; hiN0=pN0; hiN1=pN1;
  }
#pragma unroll
  for (int s=0;s<16;++s){
    int tt=s>>2, i=s&3;
    out[(long)R*64 + 16*tt + 4*q + i] = h3[s];
  }
}

extern "C" void kernel_launch(void* const* d_in, const int* in_sizes, int n_in,
                              void* d_out, int out_size, void* d_ws, size_t ws_size,
                              hipStream_t stream) {
  const void* behavior = d_in[0];
  const void* target   = d_in[1];
  const int*  lengths  = (const int*)d_in[2];
  const void* Wih = d_in[3];
  const void* Whh = d_in[4];
  const void* bih = d_in[5];
  const void* bhh = d_in[6];
  const void* A1  = d_in[7];
  const void* b1  = d_in[8];
  const void* A2  = d_in[9];
  const void* Wr  = d_in[10];
  const void* br  = d_in[11];
  const void* Wz  = d_in[12];
  const void* bz  = d_in[13];
  const void* Wn  = d_in[14];
  const void* bn  = d_in[15];

  int* flag = (int*)d_ws;
  unsigned short* hidden = (unsigned short*)((char*)d_ws + 256);
  float* attw = (float*)((char*)d_ws + 256 + (size_t)NB*SLEN*64*2);
  int* perm = (int*)((char*)d_ws + 256 + (size_t)NB*SLEN*64*2 + (size_t)NB*SLEN*4);
  size_t needed = 256 + (size_t)NB*SLEN*64*2 + (size_t)NB*SLEN*4 + (size_t)NB*4;
  if (ws_size < needed) return;

  k0_detect<<<1, 256, 0, stream>>>((const unsigned int*)behavior, 4096, flag);
  k0_sort  <<<1, 256, 0, stream>>>(lengths, perm);
  k1_gru  <<<NB/16, 64, 0, stream>>>(behavior, Wih, Whh, bih, bhh, lengths, perm, flag, hidden);
  k2_att  <<<NB,   256, 0, stream>>>(hidden, target, A1, b1, A2, lengths, flag, attw);
  k3_agru <<<NB/16, 64, 0, stream>>>(hidden, attw, Wr, br, Wz, bz, Wn, bn, lengths, perm, flag,
                                     (float*)d_out);
}

// Round 7
// 355.304 us; speedup vs baseline: 1.9120x; 1.9120x over previous
//
#include <hip/hip_runtime.h>

#define SLEN 200
#define NB   2048

typedef short  bf8s   __attribute__((ext_vector_type(8)));
typedef __bf16 bf16x8 __attribute__((ext_vector_type(8)));
typedef float  f4     __attribute__((ext_vector_type(4)));

__device__ __forceinline__ short fb1(float x){ __bf16 b=(__bf16)x; return __builtin_bit_cast(short,b); }
__device__ __forceinline__ float b2f(unsigned short b){
  return __builtin_bit_cast(float, ((unsigned int)b)<<16);
}
__device__ __forceinline__ float ldf(const void* p, long i, bool bf){
  return bf ? b2f(((const unsigned short*)p)[i]) : ((const float*)p)[i];
}
__device__ __forceinline__ bf8s loadfrag(const void* p, long i, bool bf){
  bf8s r;
  if (bf) {
    r = *(const bf8s*)((const unsigned short*)p + i);
  } else {
    const float* q = (const float*)p + i;
#pragma unroll
    for (int k=0;k<8;k++) r[k] = fb1(q[k]);
  }
  return r;
}
__device__ __forceinline__ float rcp_(float x){ return __builtin_amdgcn_rcpf(x); }
__device__ __forceinline__ float sigm(float x){ return rcp_(1.f + __expf(-x)); }
__device__ __forceinline__ float tanh_(float x){ return 1.f - 2.f*rcp_(1.f + __expf(2.f*x)); }
__device__ __forceinline__ f4 MF(bf8s a, bf8s b, f4 c){
  return __builtin_amdgcn_mfma_f32_16x16x32_bf16(
    __builtin_bit_cast(bf16x8,a), __builtin_bit_cast(bf16x8,b), c, 0,0,0);
}
// lgkm-only barrier: global loads/stores (vmcnt) stay in flight across it.
__device__ __forceinline__ void sync_lds(){
  asm volatile("s_waitcnt lgkmcnt(0)" ::: "memory");
  __builtin_amdgcn_s_barrier();
  __builtin_amdgcn_sched_barrier(0);
}
// MFMA 16x16x32 layouts (validated r3-r5): A/B: nonK=lane&15, k=8*(lane>>4)+j;
// D: col=lane&15, row=4*(lane>>4)+reg.

// ---------------- K0: input dtype detector ----------------
__global__ void k0_detect(const unsigned int* wds, int n, int* flag){
  __shared__ int cnt[256];
  int c = 0;
  for (int i = threadIdx.x; i < n; i += 256){
    unsigned e = (wds[i] >> 7) & 0xFFu;
    c += (e >= 96u && e <= 160u) ? 1 : 0;
  }
  cnt[threadIdx.x] = c;
  __syncthreads();
  for (int s = 128; s > 0; s >>= 1){
    if (threadIdx.x < s) cnt[threadIdx.x] += cnt[threadIdx.x + s];
    __syncthreads();
  }
  if (threadIdx.x == 0) flag[0] = (cnt[0]*2 > n) ? 1 : 0;
}

// ---------------- K0b: counting sort of rows by length ----------------
__global__ __launch_bounds__(256)
void k0_sort(const int* lengths, int* perm){
  __shared__ int hist[256];
  __shared__ int base[256];
  hist[threadIdx.x]=0;
  __syncthreads();
  for (int i=threadIdx.x;i<NB;i+=256) atomicAdd(&hist[lengths[i]&255],1);
  __syncthreads();
  if (threadIdx.x==0){ int acc=0; for (int j=0;j<256;++j){ base[j]=acc; acc+=hist[j]; } }
  __syncthreads();
  for (int i=threadIdx.x;i<NB;i+=256){
    int l=lengths[i]&255;
    int p=atomicAdd(&base[l],1);
    perm[p]=i;
  }
}

// ---------------- Fused DIEN: GRU scan + attention + AGRU scan ----------------
// 8 sorted rows/block. Waves 0-3: compute (wave w owns cols 16w..16w+15).
// Wave 4: writer (drains hidden-stores off the compute critical path).
__global__ __launch_bounds__(320,1)
void fused(const void* behavior, const void* target, const int* lengths,
           const void* Wih, const void* Whh, const void* bih, const void* bhh,
           const void* A1, const void* b1, const void* A2,
           const void* Wr, const void* br, const void* Wz, const void* bz,
           const void* Wn, const void* bn,
           const int* perm, const int* flag,
           unsigned short* hidden, float* out){
  const bool bf = flag[0]!=0;
  const int tid=threadIdx.x, lane=tid&63, w=tid>>6, l15=lane&15, q=lane>>4;
  const int g0 = blockIdx.x*8;

  __shared__ alignas(16) unsigned short h_lds[2][16][72];
  __shared__ alignas(16) unsigned short rh_lds[16][72];
  __shared__ float att_l[8][200];
  __shared__ float score_s[8][208];
  __shared__ float ct_s[8][64];
  __shared__ float tg_s[8][64];
  __shared__ float a2_s[64];
  __shared__ int rows8[8], lens8[8];

  if (tid<8){ int r=perm[g0+tid]; rows8[tid]=r; lens8[tid]=lengths[r]; }
  for (int i=tid;i<2*16*72;i+=320) ((unsigned short*)h_lds)[i]=0;
  __syncthreads();

  int maxlen=1;
#pragma unroll
  for (int i=0;i<8;++i) maxlen = max(maxlen, lens8[i]);
  const int ml1 = maxlen-1;
  const int jc = w*16 + l15;          // compute waves only (w<4)

  // ================= Phase 1: interest-extraction GRU =================
  bf8s wif[3][2], whf[3][2];
  float Br=0.f,Bz=0.f,Bin=0.f,Bhn=0.f;
  int Ln[4]={0,0,0,0};
  float hreg[4]={0.f,0.f,0.f,0.f};
  const unsigned short* bp=(const unsigned short*)behavior;
  const float*          fp=(const float*)behavior;
  long xorig=0;
  bf8s xC0,xC1,xN0,xN1;
  f4 c0,c1,c2,c3, n0,n1,n2,n3;

  if (w<4){
#pragma unroll
    for (int G=0;G<3;++G)
#pragma unroll
      for (int kf=0;kf<2;++kf){
        long off = (long)(G*64+jc)*64 + kf*32 + q*8;
        wif[G][kf] = loadfrag(Wih, off, bf);
        whf[G][kf] = loadfrag(Whh, off, bf);
      }
    Br  = ldf(bih,jc,bf)+ldf(bhh,jc,bf);
    Bz  = ldf(bih,64+jc,bf)+ldf(bhh,64+jc,bf);
    Bin = ldf(bih,128+jc,bf);
    Bhn = ldf(bhh,128+jc,bf);
#pragma unroll
    for (int i=0;i<4;++i) Ln[i] = lens8[(4*q+i)&7];
    xorig = ((long)rows8[l15&7]*SLEN)*64 + q*8;
    long o0 = xorig, o1 = xorig + (long)min(1,ml1)*64;
    if (bf){
      xC0=*(const bf8s*)(bp+o0); xC1=*(const bf8s*)(bp+o0+32);
      xN0=*(const bf8s*)(bp+o1); xN1=*(const bf8s*)(bp+o1+32);
    } else {
      c0=*(const f4*)(fp+o0); c1=*(const f4*)(fp+o0+4); c2=*(const f4*)(fp+o0+32); c3=*(const f4*)(fp+o0+36);
      n0=*(const f4*)(fp+o1); n1=*(const f4*)(fp+o1+4); n2=*(const f4*)(fp+o1+32); n3=*(const f4*)(fp+o1+36);
    }
  }

  for (int t=0;t<maxlen;++t){
    if (w<4){
      long po = xorig + (long)min(t+2,ml1)*64;
      bf8s pN0,pN1; f4 p0,p1,p2,p3;
      if (bf){ pN0=*(const bf8s*)(bp+po); pN1=*(const bf8s*)(bp+po+32); }
      else   { p0=*(const f4*)(fp+po); p1=*(const f4*)(fp+po+4); p2=*(const f4*)(fp+po+32); p3=*(const f4*)(fp+po+36); }

      bf8s ha0 = *(const bf8s*)&h_lds[t&1][l15][q*8];
      bf8s ha1 = *(const bf8s*)&h_lds[t&1][l15][32+q*8];
      bf8s xa0, xa1;
      if (bf){ xa0=xC0; xa1=xC1; }
      else {
#pragma unroll
        for (int j=0;j<4;++j){
          xa0[j]=fb1(c0[j]); xa0[4+j]=fb1(c1[j]);
          xa1[j]=fb1(c2[j]); xa1[4+j]=fb1(c3[j]);
        }
      }
      f4 Tr  = {Br,Br,Br,Br};
      f4 Tz  = {Bz,Bz,Bz,Bz};
      f4 Txn = {Bin,Bin,Bin,Bin};
      f4 Thn = {Bhn,Bhn,Bhn,Bhn};
      Tr =MF(xa0,wif[0][0],Tr );  Tr =MF(xa1,wif[0][1],Tr );
      Tz =MF(xa0,wif[1][0],Tz );  Tz =MF(xa1,wif[1][1],Tz );
      Txn=MF(xa0,wif[2][0],Txn);  Txn=MF(xa1,wif[2][1],Txn);
      Tr =MF(ha0,whf[0][0],Tr );  Tr =MF(ha1,whf[0][1],Tr );
      Tz =MF(ha0,whf[1][0],Tz );  Tz =MF(ha1,whf[1][1],Tz );
      Thn=MF(ha0,whf[2][0],Thn);  Thn=MF(ha1,whf[2][1],Thn);

      const int nb_=(t+1)&1;
      if (q<2){
#pragma unroll
        for (int i=0;i<4;++i){
          float rg = sigm(Tr[i]);
          float zg = sigm(Tz[i]);
          float ng = tanh_(Txn[i] + rg*Thn[i]);
          float hold = hreg[i];
          float hnew = (1.f-zg)*ng + zg*hold;
          float hv = (t < Ln[i]) ? hnew : hold;
          hreg[i] = hv;
          h_lds[nb_][4*q+i][jc] = (unsigned short)fb1(hv);
        }
      }
      if (bf){ xC0=xN0; xC1=xN1; xN0=pN0; xN1=pN1; }
      else   { c0=n0;c1=n1;c2=n2;c3=n3; n0=p0;n1=p1;n2=p2;n3=p3; }
    } else {
      // writer wave: store h_{t-1} (valid rows only) from the buffer the
      // compute waves are reading (not the one they're writing).
      if (t>0){
        int row=lane>>3, c8=(lane&7)*8;
        uint4 v = *(const uint4*)&h_lds[t&1][row][c8];
        if (t-1 < lens8[row])
          *(uint4*)&hidden[((long)rows8[row]*SLEN + (t-1))*64 + c8] = v;
      }
    }
    sync_lds();
  }
  if (w==4){
    int row=lane>>3, c8=(lane&7)*8;
    uint4 v = *(const uint4*)&h_lds[maxlen&1][row][c8];
    if (maxlen-1 < lens8[row])
      *(uint4*)&hidden[((long)rows8[row]*SLEN + (maxlen-1))*64 + c8] = v;
    asm volatile("s_waitcnt vmcnt(0)" ::: "memory");
  }
  __syncthreads();   // hidden fully written & visible (L2) to all waves

  // ================= Phase 2: attention MLP + masked softmax =================
  for (int i=tid;i<8*64;i+=320)
    tg_s[i>>6][i&63] = ldf(target,(long)rows8[i>>6]*64 + (i&63), bf);
  if (tid<64) a2_s[tid]=ldf(A2,tid,bf);
  __syncthreads();

  if (w<4){
    // per-row target contribution ct[r][a] = b1[a] + tg[r]·A1[a,64:]
#pragma unroll
    for (int rr=0;rr<2;++rr){
      int r = 2*w+rr;
      float acc = ldf(b1,lane,bf);
      for (int k=0;k<64;++k) acc += tg_s[r][k]*ldf(A1,(long)lane*128+64+k,bf);
      ct_s[r][lane]=acc;
    }
    bf8s a1f[4][2];
#pragma unroll
    for (int nt=0;nt<4;++nt)
#pragma unroll
      for (int kf=0;kf<2;++kf)
        a1f[nt][kf] = loadfrag(A1,(long)(nt*16+l15)*128 + kf*32 + q*8, bf);

#pragma unroll
    for (int rr=0;rr<2;++rr){
      int r = 2*w+rr, lenr = lens8[r];
      int mtr = (lenr+15)>>4; if (mtr>13) mtr=13;
      for (int mt=0; mt<mtr; ++mt){
        const unsigned short* hp = &hidden[((long)rows8[r]*SLEN + mt*16+l15)*64 + q*8];
        bf8s h0 = *(const bf8s*)hp;
        bf8s h1 = *(const bf8s*)(hp+32);
        f4 acc[4];
#pragma unroll
        for (int nt=0;nt<4;++nt){
          f4 a={0.f,0.f,0.f,0.f};
          a=MF(h0,a1f[nt][0],a); a=MF(h1,a1f[nt][1],a); acc[nt]=a;
        }
#pragma unroll
        for (int i=0;i<4;++i){
          float s=0.f;
#pragma unroll
          for (int nt=0;nt<4;++nt){
            int au = nt*16 + l15;
            s += fmaxf(acc[nt][i]+ct_s[r][au],0.f)*a2_s[au];
          }
#pragma unroll
          for (int d=1; d<16; d<<=1) s += __shfl_xor(s,d);
          if (l15==0) score_s[r][mt*16+4*q+i] = s;
        }
      }
      // masked softmax over this row (within the wave)
      int t0=lane, t1=64+lane, t2=128+lane, t3=192+lane;
      float v0=(t0<lenr)?score_s[r][t0]:-3e38f;
      float v1=(t1<lenr)?score_s[r][t1]:-3e38f;
      float v2=(t2<lenr)?score_s[r][t2]:-3e38f;
      float v3=(t3<lenr)?score_s[r][t3]:-3e38f;
      float m = fmaxf(fmaxf(v0,v1),fmaxf(v2,v3));
#pragma unroll
      for (int d=32;d>0;d>>=1) m = fmaxf(m,__shfl_xor(m,d));
      float e0=(t0<lenr)?__expf(v0-m):0.f;
      float e1=(t1<lenr)?__expf(v1-m):0.f;
      float e2=(t2<lenr)?__expf(v2-m):0.f;
      float e3=(t3<lenr)?__expf(v3-m):0.f;
      float S = e0+e1+e2+e3;
#pragma unroll
      for (int d=32;d>0;d>>=1) S += __shfl_xor(S,d);
      float Si = rcp_(S);
      att_l[r][t0] = e0*Si;
      att_l[r][t1] = e1*Si;
      if (t2<200) att_l[r][t2] = e2*Si;
      if (t3<200) att_l[r][t3] = e3*Si;
    }
  }
  __syncthreads();   // att_l complete

  // ================= Phase 3: attentional GRU =================
  for (int i=tid;i<2*16*72;i+=320) ((unsigned short*)h_lds)[i]=0;
  for (int i=tid;i<16*72;i+=320)   ((unsigned short*)rh_lds)[i]=0;

  bf8s wrf[2][2], wzf[2][2], wnf[2][2];
  float Brv=0.f,Bzv=0.f,Bnv=0.f;
  float h3[4]={0.f,0.f,0.f,0.f};
  long horig=0;
  bf8s hb00,hb01,hb10,hb11;
  if (w<4){
#pragma unroll
    for (int hh=0;hh<2;++hh)
#pragma unroll
      for (int kf=0;kf<2;++kf){
        long off = (long)jc*128 + hh*64 + kf*32 + q*8;
        wrf[hh][kf]=loadfrag(Wr,off,bf);
        wzf[hh][kf]=loadfrag(Wz,off,bf);
        wnf[hh][kf]=loadfrag(Wn,off,bf);
      }
    Brv=ldf(br,jc,bf); Bzv=ldf(bz,jc,bf); Bnv=ldf(bn,jc,bf);
    horig = ((long)rows8[l15&7]*SLEN)*64 + q*8;
    long o0=horig, o1=horig+(long)min(1,ml1)*64;
    hb00=*(const bf8s*)(hidden+o0); hb01=*(const bf8s*)(hidden+o0+32);
    hb10=*(const bf8s*)(hidden+o1); hb11=*(const bf8s*)(hidden+o1+32);
  }
  __syncthreads();   // h_lds/rh_lds zero visible

  for (int t=0;t<maxlen;++t){
    if (w<4){
      long po = horig + (long)min(t+2,ml1)*64;
      bf8s pN0=*(const bf8s*)(hidden+po), pN1=*(const bf8s*)(hidden+po+32);

      bf8s ha0=*(const bf8s*)&h_lds[t&1][l15][q*8];
      bf8s ha1=*(const bf8s*)&h_lds[t&1][l15][32+q*8];

      f4 Tr = {Brv,Brv,Brv,Brv};
      f4 Tz = {Bzv,Bzv,Bzv,Bzv};
      f4 Tn = {Bnv,Bnv,Bnv,Bnv};
      Tr=MF(hb00,wrf[0][0],Tr); Tr=MF(hb01,wrf[0][1],Tr);
      Tz=MF(hb00,wzf[0][0],Tz); Tz=MF(hb01,wzf[0][1],Tz);
      Tn=MF(hb00,wnf[0][0],Tn); Tn=MF(hb01,wnf[0][1],Tn);
      Tr=MF(ha0, wrf[1][0],Tr); Tr=MF(ha1, wrf[1][1],Tr);
      Tz=MF(ha0, wzf[1][0],Tz); Tz=MF(ha1, wzf[1][1],Tz);

      float zs[4], hs[4];
      if (q<2){
#pragma unroll
        for (int i=0;i<4;++i){
          int s4 = 4*q+i;
          float rg = sigm(Tr[i]);
          float ai = att_l[s4][t];
          float zg = sigm(Tz[i]) * ai;
          float hold = h3[i];
          zs[i]=zg; hs[i]=hold;
          rh_lds[s4][jc] = (unsigned short)fb1(rg*hold);
        }
      }
      sync_lds();                            // rh visible

      bf8s ra0=*(const bf8s*)&rh_lds[l15][q*8];
      bf8s ra1=*(const bf8s*)&rh_lds[l15][32+q*8];
      Tn=MF(ra0,wnf[1][0],Tn); Tn=MF(ra1,wnf[1][1],Tn);

      const int nb_=(t+1)&1;
      if (q<2){
#pragma unroll
        for (int i=0;i<4;++i){
          float ng = tanh_(Tn[i]);
          float hnew = hs[i] + zs[i]*(ng - hs[i]);   // zg==0 -> exact hold
          h3[i] = hnew;
          h_lds[nb_][4*q+i][jc] = (unsigned short)fb1(hnew);
        }
      }
      hb00=hb10; hb01=hb11; hb10=pN0; hb11=pN1;
      sync_lds();                            // h visible
    } else {
      sync_lds();
      sync_lds();
    }
  }
  if (w<4 && q<2){
#pragma unroll
    for (int i=0;i<4;++i)
      out[(long)rows8[4*q+i]*64 + jc] = h3[i];
  }
}

extern "C" void kernel_launch(void* const* d_in, const int* in_sizes, int n_in,
                              void* d_out, int out_size, void* d_ws, size_t ws_size,
                              hipStream_t stream) {
  const void* behavior = d_in[0];
  const void* target   = d_in[1];
  const int*  lengths  = (const int*)d_in[2];
  const void* Wih = d_in[3];
  const void* Whh = d_in[4];
  const void* bih = d_in[5];
  const void* bhh = d_in[6];
  const void* A1  = d_in[7];
  const void* b1  = d_in[8];
  const void* A2  = d_in[9];
  const void* Wr  = d_in[10];
  const void* br  = d_in[11];
  const void* Wz  = d_in[12];
  const void* bz  = d_in[13];
  const void* Wn  = d_in[14];
  const void* bn  = d_in[15];

  int* flag = (int*)d_ws;
  unsigned short* hidden = (unsigned short*)((char*)d_ws + 256);
  int* perm = (int*)((char*)d_ws + 256 + (size_t)NB*SLEN*64*2);
  size_t needed = 256 + (size_t)NB*SLEN*64*2 + (size_t)NB*4;
  if (ws_size < needed) return;

  k0_detect<<<1, 256, 0, stream>>>((const unsigned int*)behavior, 4096, flag);
  k0_sort  <<<1, 256, 0, stream>>>(lengths, perm);
  fused<<<NB/8, 320, 0, stream>>>(behavior, target, lengths,
                                  Wih, Whh, bih, bhh, A1, b1, A2,
                                  Wr, br, Wz, bz, Wn, bn,
                                  perm, flag, hidden, (float*)d_out);
}